// Round 15
// baseline (401.089 us; speedup 1.0000x reference)
//
#include <hip/hip_runtime.h>

#define N_USERS 100000
#define N_ITEMS 50000
#define N_NODES 150000
#define N_EDGES 2400000
#define EMB 64
#define LEAKY 0.3f

#define RB_SHIFT 7                                         // 128 rows / bucket
#define RB (1 << RB_SHIFT)
#define NBKT ((N_NODES + RB - 1) >> RB_SHIFT)              // 1172
#define L1_CHUNK 16384
#define NCH ((N_EDGES + L1_CHUNK - 1) / L1_CHUNK)          // 147 chunks
#define SCAN_ITEMS ((NBKT + 1023) / 1024)                  // 2
#define COL_MASK 0x3FFFFu                                  // col < 2^18
#define NTILE (N_NODES / 16)                               // 9375 (exact)

typedef unsigned short u16;
typedef unsigned int   u32;
typedef __attribute__((ext_vector_type(8))) short short8v;
typedef __attribute__((ext_vector_type(4))) float f32x4;
typedef __attribute__((ext_vector_type(2))) float v2f;
typedef __attribute__((ext_vector_type(4))) u32   u32x4;   // nontemporal-safe

__device__ __forceinline__ u16 f32_to_bf16_rne(float f) {
    u32 u = __float_as_uint(f);
    u32 r = (u + 0x7FFFu + ((u >> 16) & 1u)) >> 16;
    return (u16)r;
}
__device__ __forceinline__ float bf16_lo(u32 x) { return __uint_as_float(x << 16); }
__device__ __forceinline__ u32 pack_bf16(float lo, float hi) {
    return (u32)f32_to_bf16_rne(lo) | ((u32)f32_to_bf16_rne(hi) << 16);
}
// unpack a bf16-pair dword into a packed f32 pair (feeds v_pk_fma_f32)
__device__ __forceinline__ v2f up2(u32 w) {
    v2f r;
    r.x = __uint_as_float(w << 16);
    r.y = __uint_as_float(w & 0xFFFF0000u);
    return r;
}

// ===========================================================================
// e0 -> bf16 (user ++ item) and W0/W1 -> bf16, one dispatch
// ===========================================================================
__global__ __launch_bounds__(256) void conv_all(
    const float* __restrict__ uemb, const float* __restrict__ iemb,
    const float* __restrict__ W0, const float* __restrict__ W1,
    u16* __restrict__ ebf, u16* __restrict__ Wbf0, u16* __restrict__ Wbf1)
{
    const int gid = blockIdx.x * 256 + threadIdx.x;
    const int i = gid * 4;
    if (i < N_NODES * EMB) {
        const float* src = (i < N_USERS * EMB) ? uemb + i : iemb + (i - N_USERS * EMB);
        const float4 v = *(const float4*)src;
        ushort4 w;
        w.x = f32_to_bf16_rne(v.x);
        w.y = f32_to_bf16_rne(v.y);
        w.z = f32_to_bf16_rne(v.z);
        w.w = f32_to_bf16_rne(v.w);
        *(ushort4*)(ebf + i) = w;
    }
    if (gid < EMB * EMB) {
        Wbf0[gid] = f32_to_bf16_rne(W0[gid]);
        Wbf1[gid] = f32_to_bf16_rne(W1[gid]);
    }
}

// ===========================================================================
// Per-chunk bucket histogram -> H[chunk][NBKT] (no global atomics)
// ===========================================================================
__global__ __launch_bounds__(1024) void bkt_hist(
    const int* __restrict__ rows, int* __restrict__ H)
{
    __shared__ int cnt[NBKT];
    const int t = threadIdx.x;
    const int c = blockIdx.x;
    for (int b = t; b < NBKT; b += 1024) cnt[b] = 0;
    __syncthreads();

    const int e0 = c * L1_CHUNK;
    const int e1 = (e0 + L1_CHUNK < N_EDGES) ? e0 + L1_CHUNK : N_EDGES;
    for (int i = e0 + t; i < e1; i += 1024)
        atomicAdd(&cnt[rows[i] >> RB_SHIFT], 1);
    __syncthreads();

    for (int b = t; b < NBKT; b += 1024) H[c * NBKT + b] = cnt[b];
}

// ===========================================================================
// scan_plus (single block): bucket totals -> bkt_ptr; B[c][b] bases.
// ===========================================================================
__global__ __launch_bounds__(1024) void scan_plus(
    const int* __restrict__ H, int* __restrict__ bkt_ptr,
    int* __restrict__ B)
{
    __shared__ int lds[1024];
    const int t = threadIdx.x;

    int v[SCAN_ITEMS];
    int s = 0;
    #pragma unroll
    for (int j = 0; j < SCAN_ITEMS; ++j) {
        const int idx = t * SCAN_ITEMS + j;
        int tot = 0;
        if (idx < NBKT) {
            int c = 0;
            int s0 = 0, s1 = 0, s2 = 0, s3 = 0;
            for (; c + 4 <= NCH; c += 4) {
                s0 += H[(c + 0) * NBKT + idx];
                s1 += H[(c + 1) * NBKT + idx];
                s2 += H[(c + 2) * NBKT + idx];
                s3 += H[(c + 3) * NBKT + idx];
            }
            for (; c < NCH; ++c) s0 += H[c * NBKT + idx];
            tot = (s0 + s1) + (s2 + s3);
        }
        v[j] = tot;
        s += tot;
    }
    lds[t] = s;
    __syncthreads();
    for (int off = 1; off < 1024; off <<= 1) {
        int x = 0;
        if (t >= off) x = lds[t - off];
        __syncthreads();
        lds[t] += x;
        __syncthreads();
    }
    int run = lds[t] - s;   // exclusive prefix of this thread's group

    #pragma unroll
    for (int j = 0; j < SCAN_ITEMS; ++j) {
        const int idx = t * SCAN_ITEMS + j;
        if (idx < NBKT) {
            bkt_ptr[idx] = run;
            int r2 = run;
            for (int c = 0; c < NCH; ++c) {
                B[c * NBKT + idx] = r2;
                r2 += H[c * NBKT + idx];
            }
            run += v[j];
        }
    }
    if (t == 0) bkt_ptr[NBKT] = N_EDGES;
}

// ===========================================================================
// Partition (single edge pass, no global atomics)
// record = (val, (localrow<<18)|col), localrow 7 bits
// ===========================================================================
__global__ __launch_bounds__(1024) void partition_l1(
    const float* __restrict__ vals, const int* __restrict__ rows,
    const int* __restrict__ cols, const int* __restrict__ B,
    float* __restrict__ svc)             // float2 records, raw float* base
{
    __shared__ int base[NBKT];
    __shared__ int cnt[NBKT];
    const int t = threadIdx.x;
    const int c = blockIdx.x;
    for (int b = t; b < NBKT; b += 1024) {
        base[b] = B[c * NBKT + b];
        cnt[b]  = 0;
    }
    __syncthreads();

    const int e0 = c * L1_CHUNK;
    const int e1 = (e0 + L1_CHUNK < N_EDGES) ? e0 + L1_CHUNK : N_EDGES;
    for (int i = e0 + t; i < e1; i += 1024) {
        const int r = rows[i];
        const int b = r >> RB_SHIFT;
        const int pos = base[b] + atomicAdd(&cnt[b], 1);
        const u32 packed = ((u32)(r & (RB - 1)) << 18) | (u32)cols[i];
        v2f rec;
        rec.x = vals[i];
        rec.y = __uint_as_float(packed);
        __builtin_nontemporal_store(rec, (v2f*)(svc + 2 * (size_t)pos));
    }
}

// ===========================================================================
// place_l2: per-row count (LDS) -> LDS scan -> row_ptr -> in-bucket
// placement via LDS heads. RB=128 -> 1172 blocks (2x TLP vs RB=256).
// ===========================================================================
__global__ __launch_bounds__(256) void place_l2(
    const int* __restrict__ bkt_ptr, const float* __restrict__ svc,
    float* __restrict__ sedge, int* __restrict__ row_ptr)
{
    __shared__ int cnt[RB];
    __shared__ int heads[RB];
    const int b     = blockIdx.x;
    const int rbase = b << RB_SHIFT;
    const int t     = threadIdx.x;

    if (t < RB) cnt[t] = 0;
    __syncthreads();

    const int lo = bkt_ptr[b];
    const int hi = bkt_ptr[b + 1];

    for (int i = lo + t; i < hi; i += 256) {
        const u32 pk = __float_as_uint(svc[2 * (size_t)i + 1]);
        atomicAdd(&cnt[pk >> 18], 1);
    }
    __syncthreads();

    int v = 0;
    if (t < RB) v = cnt[t];
    for (int off = 1; off < RB; off <<= 1) {
        int x = 0;
        if (t < RB && t >= off) x = cnt[t - off];
        __syncthreads();
        if (t < RB) cnt[t] += x;
        __syncthreads();
    }
    if (t < RB) {
        const int excl = cnt[t] - v;
        heads[t] = lo + excl;
        const int gr = rbase + t;
        if (gr <= N_NODES) row_ptr[gr] = lo + excl;
    }
    __syncthreads();

    for (int i = lo + t; i < hi; i += 256) {
        const v2f vc = __builtin_nontemporal_load((const v2f*)(svc + 2 * (size_t)i));
        const int lr  = (int)(__float_as_uint(vc.y) >> 18);
        const int pos = atomicAdd(&heads[lr], 1);
        __builtin_nontemporal_store(vc, (v2f*)(sedge + 2 * (size_t)pos));
    }
}

// ===========================================================================
// Pull-SpMM over bf16 source, dwordx4 gather, single predicated 16-wide
// loop (both gathers always in flight — fixes the low-degree tail MLP),
// packed v2f accumulate (v_pk_fma_f32).
// ===========================================================================
__global__ __launch_bounds__(256) void spmm_bf16(
    const int* __restrict__ row_ptr,     // N_NODES+1
    const float* __restrict__ sedge,     // (val, packed) float2 records
    const u16* __restrict__ ebf,         // [N_NODES][64] bf16
    u16* __restrict__ tbf)               // [N_NODES][64] bf16
{
    const int tid  = threadIdx.x;
    const int lane = tid & 63;
    const int row  = blockIdx.x * 4 + (tid >> 6);
    if (row >= N_NODES) return;

    const int g = lane >> 3;    // edge slot 0..7
    const int q = lane & 7;     // feature octet -> features 8q..8q+7

    const int beg = row_ptr[row];
    const int end = row_ptr[row + 1];

    v2f A0 = {0.f, 0.f}, A1 = {0.f, 0.f}, A2 = {0.f, 0.f}, A3 = {0.f, 0.f};

    for (int k = beg; k < end; k += 16) {
        const int  kA  = k + g;
        const int  kB  = k + 8 + g;
        const bool onA = kA < end;
        const bool onB = kB < end;
        const v2f mA = __builtin_nontemporal_load(
            (const v2f*)(sedge + 2 * (size_t)(onA ? kA : end - 1)));
        const v2f mB = __builtin_nontemporal_load(
            (const v2f*)(sedge + 2 * (size_t)(onB ? kB : end - 1)));
        const float vA = onA ? mA.x : 0.f;
        const float vB = onB ? mB.x : 0.f;
        const u32 iA = __float_as_uint(mA.y) & COL_MASK;
        const u32 iB = __float_as_uint(mB.y) & COL_MASK;
        const u32x4 xA = *((const u32x4*)(ebf + (size_t)iA * EMB) + q);
        const u32x4 xB = *((const u32x4*)(ebf + (size_t)iB * EMB) + q);
        const v2f vvA = {vA, vA};
        const v2f vvB = {vB, vB};
        A0 = vvA * up2(xA.x) + A0;
        A1 = vvA * up2(xA.y) + A1;
        A2 = vvA * up2(xA.z) + A2;
        A3 = vvA * up2(xA.w) + A3;
        A0 = vvB * up2(xB.x) + A0;
        A1 = vvB * up2(xB.y) + A1;
        A2 = vvB * up2(xB.z) + A2;
        A3 = vvB * up2(xB.w) + A3;
    }

    // reduce across the 8 edge slots (xor 8,16,32) per f32 component
    float s0 = A0.x, s1 = A0.y, s2 = A1.x, s3 = A1.y;
    float s4 = A2.x, s5 = A2.y, s6 = A3.x, s7 = A3.y;
    s0 += __shfl_xor(s0, 8); s0 += __shfl_xor(s0, 16); s0 += __shfl_xor(s0, 32);
    s1 += __shfl_xor(s1, 8); s1 += __shfl_xor(s1, 16); s1 += __shfl_xor(s1, 32);
    s2 += __shfl_xor(s2, 8); s2 += __shfl_xor(s2, 16); s2 += __shfl_xor(s2, 32);
    s3 += __shfl_xor(s3, 8); s3 += __shfl_xor(s3, 16); s3 += __shfl_xor(s3, 32);
    s4 += __shfl_xor(s4, 8); s4 += __shfl_xor(s4, 16); s4 += __shfl_xor(s4, 32);
    s5 += __shfl_xor(s5, 8); s5 += __shfl_xor(s5, 16); s5 += __shfl_xor(s5, 32);
    s6 += __shfl_xor(s6, 8); s6 += __shfl_xor(s6, 16); s6 += __shfl_xor(s6, 32);
    s7 += __shfl_xor(s7, 8); s7 += __shfl_xor(s7, 16); s7 += __shfl_xor(s7, 32);

    if (g == 0) {
        u32x4 w;
        w.x = pack_bf16(s0, s1);
        w.y = pack_bf16(s2, s3);
        w.z = pack_bf16(s4, s5);
        w.w = pack_bf16(s6, s7);
        __builtin_nontemporal_store(w, (u32x4*)(tbf + (size_t)row * EMB + 8 * q));
    }
}

// ===========================================================================
// Dense stage via MFMA (round-12 proven): e1 = t @ W^T fused with LeakyReLU
// + e0-add + 0.25-mean + e2->bf16 writeback. 8x mfma_16x16x32_bf16, no LDS.
// ===========================================================================
template <bool FIRST>
__global__ __launch_bounds__(256) void dense_mfma(
    const u16* __restrict__ tbf,     // [N_NODES][64] bf16
    const u16* __restrict__ Wbf,     // [64][64] bf16
    u16* ebf,                        // FIRST: e0 read + e2 write (same elem)
    float* __restrict__ out)
{
    const int tid  = threadIdx.x;
    const int l    = tid & 63;
    const int tile = blockIdx.x * 4 + (tid >> 6);
    if (tile >= NTILE) return;
    const int row0 = tile * 16;

    const int lr = l & 15;
    const int lk = l >> 4;

    short8v bfrag[4][2];
    #pragma unroll
    for (int c = 0; c < 4; ++c)
        #pragma unroll
        for (int kh = 0; kh < 2; ++kh)
            bfrag[c][kh] = *(const short8v*)(Wbf + (size_t)(16 * c + lr) * EMB
                                             + 32 * kh + 8 * lk);

    const u16* trow = tbf + (size_t)(row0 + lr) * EMB;
    const short8v afrag0 = *(const short8v*)(trow + 8 * lk);
    const short8v afrag1 = *(const short8v*)(trow + 32 + 8 * lk);

    f32x4 acc[4];
    #pragma unroll
    for (int c = 0; c < 4; ++c) {
        f32x4 z = {0.f, 0.f, 0.f, 0.f};
        z = __builtin_amdgcn_mfma_f32_16x16x32_bf16(afrag0, bfrag[c][0], z, 0, 0, 0);
        z = __builtin_amdgcn_mfma_f32_16x16x32_bf16(afrag1, bfrag[c][1], z, 0, 0, 0);
        acc[c] = z;
    }

    #pragma unroll
    for (int c = 0; c < 4; ++c) {
        #pragma unroll
        for (int r = 0; r < 4; ++r) {
            const int row = row0 + 4 * lk + r;
            const size_t idx = (size_t)row * EMB + 16 * c + lr;
            const float e1v = acc[c][r];
            if (FIRST) {
                const float e2v = (e1v >= 0.f) ? e1v : LEAKY * e1v;
                const float e0v = bf16_lo((u32)ebf[idx]);   // e0 (bf16)
                out[idx] = 0.25f * (e0v + e1v + e2v);
                ebf[idx] = f32_to_bf16_rne(e2v);            // e2 for stage 2
            } else {
                out[idx] += 0.25f * e1v;
            }
        }
    }
}

// ===========================================================================
// Fallback (round-1 proven): atomic SpMM + f32 dense, if ws too small.
// ===========================================================================
__global__ __launch_bounds__(256) void spmm_atomic(
    const float* __restrict__ vals, const int* __restrict__ rows,
    const int* __restrict__ cols, const float* __restrict__ src_a,
    const float* __restrict__ src_b, float* __restrict__ dst)
{
    const int tid  = threadIdx.x;
    const int lane = tid & 63;
    const int e    = blockIdx.x * 4 + (tid >> 6);
    if (e >= N_EDGES) return;
    const float v = vals[e];
    const int   c = cols[e];
    const int   r = rows[e];
    const float* src = (src_b != nullptr && c >= N_USERS)
                           ? src_b + (size_t)(c - N_USERS) * EMB
                           : src_a + (size_t)c * EMB;
    unsafeAtomicAdd(&dst[(size_t)r * EMB + lane], v * src[lane]);
}

template <bool FIRST>
__global__ __launch_bounds__(256) void dense_f32(
    const float* __restrict__ t, const float* __restrict__ W,
    const float* __restrict__ user_emb, const float* __restrict__ item_emb,
    float* __restrict__ e2, float* __restrict__ out)
{
    __shared__ float wT[64][65];
    __shared__ float trow[16][64];

    const int tid = threadIdx.x;
    for (int k = tid; k < 64 * 64; k += 256) {
        const int i = k >> 6, j = k & 63;
        wT[j][i] = W[k];
    }
    const int row_base = blockIdx.x * 16;
    for (int k = tid; k < 16 * 64; k += 256) {
        const int r = k >> 6, j = k & 63;
        const int row = row_base + r;
        trow[r][j] = (row < N_NODES) ? t[(size_t)row * EMB + j] : 0.f;
    }
    __syncthreads();

    const int i  = tid & 63;
    const int r0 = tid >> 6;

    #pragma unroll
    for (int rr = 0; rr < 4; ++rr) {
        const int r   = r0 * 4 + rr;
        const int row = row_base + r;
        if (row >= N_NODES) continue;
        float acc = 0.f;
        #pragma unroll
        for (int j = 0; j < 64; ++j)
            acc = fmaf(trow[r][j], wT[j][i], acc);
        const size_t idx = (size_t)row * EMB + i;
        if (FIRST) {
            const float e1v = acc;
            const float e2v = (e1v >= 0.f) ? e1v : LEAKY * e1v;
            const float e0v = (row < N_USERS)
                                  ? user_emb[idx]
                                  : item_emb[(size_t)(row - N_USERS) * EMB + i];
            e2[idx]  = e2v;
            out[idx] = 0.25f * (e0v + e1v + e2v);
        } else {
            out[idx] += 0.25f * acc;
        }
    }
}

// ===========================================================================
extern "C" void kernel_launch(void* const* d_in, const int* in_sizes, int n_in,
                              void* d_out, int out_size, void* d_ws, size_t ws_size,
                              hipStream_t stream)
{
    const float* user_emb = (const float*)d_in[0];
    const float* item_emb = (const float*)d_in[1];
    const float* W0       = (const float*)d_in[2];
    const float* W1       = (const float*)d_in[3];
    const float* adj_vals = (const float*)d_in[4];
    const int*   adj_rows = (const int*)d_in[5];
    const int*   adj_cols = (const int*)d_in[6];
    float*       out      = (float*)d_out;

    const size_t mat_bytes = (size_t)N_NODES * EMB * sizeof(float);   // 38.4 MB
    const size_t ebf_bytes = (size_t)N_NODES * EMB * sizeof(u16);     // 19.2 MB
    const size_t edge8     = (size_t)N_EDGES * 8;                     // 19.2 MB
    const size_t hmat      = (size_t)NCH * NBKT * sizeof(int);        // 0.69 MB

    // layout: [tbf 19.2 | svc transient] [sedge 19.2] [ebf 19.2] [aux] [Wbf]
    const size_t off_tbf    = 0;
    const size_t off_svc    = 0;                       // transient, inside tbf
    const size_t off_sedge  = off_tbf + ebf_bytes;
    const size_t off_ebf    = off_sedge + edge8;
    const size_t off_rowptr = off_ebf + ebf_bytes;
    const size_t off_H      = off_rowptr + (size_t)(N_NODES + 1) * sizeof(int);
    const size_t off_B      = off_H + hmat;
    const size_t off_ptr    = off_B + hmat;
    const size_t off_wbf    = (off_ptr + (size_t)(NBKT + 1) * sizeof(int) + 15) & ~(size_t)15;
    const size_t required   = off_wbf + 2 * (size_t)EMB * EMB * sizeof(u16); // ~60.3 MB

    const int spmm_blocks   = (N_NODES + 3) / 4;       // 37500
    const int densem_blocks = (NTILE + 3) / 4;         // 2344
    const int conv_blocks   = (N_NODES * EMB / 4 + 255) / 256;

    if (ws_size >= required) {
        u16*   tbf     = (u16*)((char*)d_ws + off_tbf);
        float* svc     = (float*)((char*)d_ws + off_svc);
        float* sedge   = (float*)((char*)d_ws + off_sedge);
        u16*   ebf     = (u16*)((char*)d_ws + off_ebf);
        int*   row_ptr = (int*)((char*)d_ws + off_rowptr);
        int*   H       = (int*)((char*)d_ws + off_H);
        int*   B       = (int*)((char*)d_ws + off_B);
        int*   bkt_ptr = (int*)((char*)d_ws + off_ptr);
        u16*   Wbf0    = (u16*)((char*)d_ws + off_wbf);
        u16*   Wbf1    = Wbf0 + EMB * EMB;

        // ---- bf16 sources (e0, W0, W1) ----
        conv_all<<<conv_blocks, 256, 0, stream>>>(
            user_emb, item_emb, W0, W1, ebf, Wbf0, Wbf1);

        // ---- bucket-sorted edge list + row_ptr (once, reused twice) ----
        bkt_hist<<<NCH, 1024, 0, stream>>>(adj_rows, H);
        scan_plus<<<1, 1024, 0, stream>>>(H, bkt_ptr, B);
        partition_l1<<<NCH, 1024, 0, stream>>>(
            adj_vals, adj_rows, adj_cols, B, svc);
        place_l2<<<NBKT, 256, 0, stream>>>(bkt_ptr, svc, sedge, row_ptr);
        // svc (inside tbf) is dead from here on

        // ---- stage 1: tbf = A @ e0 ; e1/e2/out ; e2 -> ebf (bf16) ----
        spmm_bf16<<<spmm_blocks, 256, 0, stream>>>(row_ptr, sedge, ebf, tbf);
        dense_mfma<true><<<densem_blocks, 256, 0, stream>>>(tbf, Wbf0, ebf, out);

        // ---- stage 2: tbf = A @ e2 ; out += 0.25*e3 ----
        spmm_bf16<<<spmm_blocks, 256, 0, stream>>>(row_ptr, sedge, ebf, tbf);
        dense_mfma<false><<<densem_blocks, 256, 0, stream>>>(tbf, Wbf1, ebf, out);
    } else {
        // ---- fallback: round-1 atomic path ----
        float* t  = (float*)d_ws;
        float* e2 = (float*)((char*)d_ws + mat_bytes);
        const int dense_blocks = (N_NODES + 15) / 16;

        hipMemsetAsync(t, 0, mat_bytes, stream);
        spmm_atomic<<<(N_EDGES + 3) / 4, 256, 0, stream>>>(
            adj_vals, adj_rows, adj_cols, user_emb, item_emb, t);
        dense_f32<true><<<dense_blocks, 256, 0, stream>>>(
            t, W0, user_emb, item_emb, e2, out);

        hipMemsetAsync(t, 0, mat_bytes, stream);
        spmm_atomic<<<(N_EDGES + 3) / 4, 256, 0, stream>>>(
            adj_vals, adj_rows, adj_cols, e2, nullptr, t);
        dense_f32<false><<<dense_blocks, 256, 0, stream>>>(
            t, W1, nullptr, nullptr, nullptr, out);
    }
}

// Round 16
// 228.403 us; speedup vs baseline: 1.7561x; 1.7561x over previous
//
#include <hip/hip_runtime.h>

#define N_USERS 100000
#define N_ITEMS 50000
#define N_NODES 150000
#define N_EDGES 2400000
#define EMB 64
#define LEAKY 0.3f

#define RB_SHIFT 8                                         // 256 rows / bucket
#define RB (1 << RB_SHIFT)
#define NBKT ((N_NODES + RB - 1) >> RB_SHIFT)              // 586
#define L1_CHUNK 16384
#define NCH ((N_EDGES + L1_CHUNK - 1) / L1_CHUNK)          // 147 chunks
#define COL_MASK 0x3FFFFu                                  // col < 2^18
#define NTILE (N_NODES / 16)                               // 9375 (exact)

typedef unsigned short u16;
typedef unsigned int   u32;
typedef __attribute__((ext_vector_type(8))) short short8v;
typedef __attribute__((ext_vector_type(4))) float f32x4;
typedef __attribute__((ext_vector_type(2))) float v2f;

__device__ __forceinline__ u16 f32_to_bf16_rne(float f) {
    u32 u = __float_as_uint(f);
    u32 r = (u + 0x7FFFu + ((u >> 16) & 1u)) >> 16;
    return (u16)r;
}
__device__ __forceinline__ float bf16_lo(u32 x) { return __uint_as_float(x << 16); }
__device__ __forceinline__ u32 pack_bf16(float lo, float hi) {
    return (u32)f32_to_bf16_rne(lo) | ((u32)f32_to_bf16_rne(hi) << 16);
}
// unpack a bf16-pair dword into a packed f32 pair (feeds v_pk_fma_f32)
__device__ __forceinline__ v2f up2(u32 w) {
    v2f r;
    r.x = __uint_as_float(w << 16);
    r.y = __uint_as_float(w & 0xFFFF0000u);
    return r;
}

// ===========================================================================
// e0 -> bf16 (user ++ item) and W0/W1 -> bf16, one dispatch
// ===========================================================================
__global__ __launch_bounds__(256) void conv_all(
    const float* __restrict__ uemb, const float* __restrict__ iemb,
    const float* __restrict__ W0, const float* __restrict__ W1,
    u16* __restrict__ ebf, u16* __restrict__ Wbf0, u16* __restrict__ Wbf1)
{
    const int gid = blockIdx.x * 256 + threadIdx.x;
    const int i = gid * 4;
    if (i < N_NODES * EMB) {
        const float* src = (i < N_USERS * EMB) ? uemb + i : iemb + (i - N_USERS * EMB);
        const float4 v = *(const float4*)src;
        ushort4 w;
        w.x = f32_to_bf16_rne(v.x);
        w.y = f32_to_bf16_rne(v.y);
        w.z = f32_to_bf16_rne(v.z);
        w.w = f32_to_bf16_rne(v.w);
        *(ushort4*)(ebf + i) = w;
    }
    if (gid < EMB * EMB) {
        Wbf0[gid] = f32_to_bf16_rne(W0[gid]);
        Wbf1[gid] = f32_to_bf16_rne(W1[gid]);
    }
}

// ===========================================================================
// Per-chunk bucket histogram -> H[chunk][NBKT] (no global atomics)
// ===========================================================================
__global__ __launch_bounds__(1024) void bkt_hist(
    const int* __restrict__ rows, int* __restrict__ H)
{
    __shared__ int cnt[NBKT];
    const int t = threadIdx.x;
    const int c = blockIdx.x;
    if (t < NBKT) cnt[t] = 0;
    __syncthreads();

    const int e0 = c * L1_CHUNK;
    const int e1 = (e0 + L1_CHUNK < N_EDGES) ? e0 + L1_CHUNK : N_EDGES;
    for (int i = e0 + t; i < e1; i += 1024)
        atomicAdd(&cnt[rows[i] >> RB_SHIFT], 1);
    __syncthreads();

    if (t < NBKT) H[c * NBKT + t] = cnt[t];
}

// ===========================================================================
// scan_plus (single block): bucket totals -> bkt_ptr; B[c][b] bases.
// ===========================================================================
__global__ __launch_bounds__(1024) void scan_plus(
    const int* __restrict__ H, int* __restrict__ bkt_ptr,
    int* __restrict__ B)
{
    __shared__ int lds[1024];
    const int t = threadIdx.x;

    int tot = 0;
    if (t < NBKT) {
        int s0 = 0, s1 = 0, s2 = 0, s3 = 0;
        int c = 0;
        for (; c + 4 <= NCH; c += 4) {
            s0 += H[(c + 0) * NBKT + t];
            s1 += H[(c + 1) * NBKT + t];
            s2 += H[(c + 2) * NBKT + t];
            s3 += H[(c + 3) * NBKT + t];
        }
        for (; c < NCH; ++c) s0 += H[c * NBKT + t];
        tot = (s0 + s1) + (s2 + s3);
    }
    lds[t] = (t < NBKT) ? tot : 0;
    __syncthreads();
    for (int off = 1; off < 1024; off <<= 1) {
        int x = 0;
        if (t >= off) x = lds[t - off];
        __syncthreads();
        lds[t] += x;
        __syncthreads();
    }
    const int excl = lds[t] - tot;

    if (t < NBKT) {
        bkt_ptr[t] = excl;
        int run = excl;
        int c = 0;
        for (; c + 4 <= NCH; c += 4) {
            const int h0 = H[(c + 0) * NBKT + t];
            const int h1 = H[(c + 1) * NBKT + t];
            const int h2 = H[(c + 2) * NBKT + t];
            const int h3 = H[(c + 3) * NBKT + t];
            B[(c + 0) * NBKT + t] = run;
            B[(c + 1) * NBKT + t] = run + h0;
            B[(c + 2) * NBKT + t] = run + h0 + h1;
            B[(c + 3) * NBKT + t] = run + h0 + h1 + h2;
            run += h0 + h1 + h2 + h3;
        }
        for (; c < NCH; ++c) {
            B[c * NBKT + t] = run;
            run += H[c * NBKT + t];
        }
    }
    if (t == 0) bkt_ptr[NBKT] = N_EDGES;
}

// ===========================================================================
// Partition (single edge pass, no global atomics)
// record = (val, (localrow<<18)|col)
// ===========================================================================
__global__ __launch_bounds__(1024) void partition_l1(
    const float* __restrict__ vals, const int* __restrict__ rows,
    const int* __restrict__ cols, const int* __restrict__ B,
    float2* __restrict__ svc)
{
    __shared__ int base[NBKT];
    __shared__ int cnt[NBKT];
    const int t = threadIdx.x;
    const int c = blockIdx.x;
    if (t < NBKT) {
        base[t] = B[c * NBKT + t];
        cnt[t]  = 0;
    }
    __syncthreads();

    const int e0 = c * L1_CHUNK;
    const int e1 = (e0 + L1_CHUNK < N_EDGES) ? e0 + L1_CHUNK : N_EDGES;
    for (int i = e0 + t; i < e1; i += 1024) {
        const int r = rows[i];
        const int b = r >> RB_SHIFT;
        const int pos = base[b] + atomicAdd(&cnt[b], 1);
        const u32 packed = ((u32)(r & (RB - 1)) << 18) | (u32)cols[i];
        svc[pos] = make_float2(vals[i], __uint_as_float(packed));
    }
}

// ===========================================================================
// place_l2 (round-9/13 proven): per-row count (LDS) -> LDS scan -> row_ptr
// -> in-bucket placement via LDS heads. Plain stores: the block's writes
// stay in a ~32KB range so one XCD L2 assembles full lines (no nt!).
// ===========================================================================
__global__ __launch_bounds__(256) void place_l2(
    const int* __restrict__ bkt_ptr, const float2* __restrict__ svc,
    float2* __restrict__ sedge, int* __restrict__ row_ptr)
{
    __shared__ int cnt[RB];
    __shared__ int heads[RB];
    const int b     = blockIdx.x;
    const int rbase = b << RB_SHIFT;
    const int t     = threadIdx.x;

    cnt[t] = 0;
    __syncthreads();

    const int lo = bkt_ptr[b];
    const int hi = bkt_ptr[b + 1];

    for (int i = lo + t; i < hi; i += 256)
        atomicAdd(&cnt[__float_as_uint(svc[i].y) >> 18], 1);
    __syncthreads();

    const int v = cnt[t];
    for (int off = 1; off < 256; off <<= 1) {
        int x = 0;
        if (t >= off) x = cnt[t - off];
        __syncthreads();
        cnt[t] += x;
        __syncthreads();
    }
    const int excl = cnt[t] - v;
    heads[t] = lo + excl;
    const int gr = rbase + t;
    if (gr <= N_NODES) row_ptr[gr] = lo + excl;
    __syncthreads();

    for (int i = lo + t; i < hi; i += 256) {
        const float2 vc = svc[i];
        const int lr  = (int)(__float_as_uint(vc.y) >> 18);
        const int pos = atomicAdd(&heads[lr], 1);
        sedge[pos] = vc;
    }
}

// ===========================================================================
// Pull-SpMM over bf16 source, dwordx4 gather, single predicated 16-wide
// loop (both gathers always in flight), packed v2f accumulate (pk_fma).
// Plain (cached) loads/stores — nt hurt badly in round 15.
// ===========================================================================
__global__ __launch_bounds__(256) void spmm_bf16(
    const int* __restrict__ row_ptr,     // N_NODES+1
    const float2* __restrict__ sedge,    // (val, packed) row-sorted
    const u16* __restrict__ ebf,         // [N_NODES][64] bf16
    u16* __restrict__ tbf)               // [N_NODES][64] bf16
{
    const int tid  = threadIdx.x;
    const int lane = tid & 63;
    const int row  = blockIdx.x * 4 + (tid >> 6);
    if (row >= N_NODES) return;

    const int g = lane >> 3;    // edge slot 0..7
    const int q = lane & 7;     // feature octet -> features 8q..8q+7

    const int beg = row_ptr[row];
    const int end = row_ptr[row + 1];

    v2f A0 = {0.f, 0.f}, A1 = {0.f, 0.f}, A2 = {0.f, 0.f}, A3 = {0.f, 0.f};

    for (int k = beg; k < end; k += 16) {
        const int  kA  = k + g;
        const int  kB  = k + 8 + g;
        const bool onA = kA < end;
        const bool onB = kB < end;
        const float2 mA = sedge[onA ? kA : end - 1];
        const float2 mB = sedge[onB ? kB : end - 1];
        const float vA = onA ? mA.x : 0.f;
        const float vB = onB ? mB.x : 0.f;
        const u32 iA = __float_as_uint(mA.y) & COL_MASK;
        const u32 iB = __float_as_uint(mB.y) & COL_MASK;
        const uint4 xA = *((const uint4*)(ebf + (size_t)iA * EMB) + q);
        const uint4 xB = *((const uint4*)(ebf + (size_t)iB * EMB) + q);
        const v2f vvA = {vA, vA};
        const v2f vvB = {vB, vB};
        A0 = vvA * up2(xA.x) + A0;
        A1 = vvA * up2(xA.y) + A1;
        A2 = vvA * up2(xA.z) + A2;
        A3 = vvA * up2(xA.w) + A3;
        A0 = vvB * up2(xB.x) + A0;
        A1 = vvB * up2(xB.y) + A1;
        A2 = vvB * up2(xB.z) + A2;
        A3 = vvB * up2(xB.w) + A3;
    }

    // reduce across the 8 edge slots (xor 8,16,32) per f32 component
    float s0 = A0.x, s1 = A0.y, s2 = A1.x, s3 = A1.y;
    float s4 = A2.x, s5 = A2.y, s6 = A3.x, s7 = A3.y;
    s0 += __shfl_xor(s0, 8); s0 += __shfl_xor(s0, 16); s0 += __shfl_xor(s0, 32);
    s1 += __shfl_xor(s1, 8); s1 += __shfl_xor(s1, 16); s1 += __shfl_xor(s1, 32);
    s2 += __shfl_xor(s2, 8); s2 += __shfl_xor(s2, 16); s2 += __shfl_xor(s2, 32);
    s3 += __shfl_xor(s3, 8); s3 += __shfl_xor(s3, 16); s3 += __shfl_xor(s3, 32);
    s4 += __shfl_xor(s4, 8); s4 += __shfl_xor(s4, 16); s4 += __shfl_xor(s4, 32);
    s5 += __shfl_xor(s5, 8); s5 += __shfl_xor(s5, 16); s5 += __shfl_xor(s5, 32);
    s6 += __shfl_xor(s6, 8); s6 += __shfl_xor(s6, 16); s6 += __shfl_xor(s6, 32);
    s7 += __shfl_xor(s7, 8); s7 += __shfl_xor(s7, 16); s7 += __shfl_xor(s7, 32);

    if (g == 0) {
        uint4 w;
        w.x = pack_bf16(s0, s1);
        w.y = pack_bf16(s2, s3);
        w.z = pack_bf16(s4, s5);
        w.w = pack_bf16(s6, s7);
        *(uint4*)(tbf + (size_t)row * EMB + 8 * q) = w;
    }
}

// ===========================================================================
// Dense stage via MFMA (round-12 proven): e1 = t @ W^T fused with LeakyReLU
// + e0-add + 0.25-mean + e2->bf16 writeback. 8x mfma_16x16x32_bf16, no LDS.
// ===========================================================================
template <bool FIRST>
__global__ __launch_bounds__(256) void dense_mfma(
    const u16* __restrict__ tbf,     // [N_NODES][64] bf16
    const u16* __restrict__ Wbf,     // [64][64] bf16
    u16* ebf,                        // FIRST: e0 read + e2 write (same elem)
    float* __restrict__ out)
{
    const int tid  = threadIdx.x;
    const int l    = tid & 63;
    const int tile = blockIdx.x * 4 + (tid >> 6);
    if (tile >= NTILE) return;
    const int row0 = tile * 16;

    const int lr = l & 15;
    const int lk = l >> 4;

    short8v bfrag[4][2];
    #pragma unroll
    for (int c = 0; c < 4; ++c)
        #pragma unroll
        for (int kh = 0; kh < 2; ++kh)
            bfrag[c][kh] = *(const short8v*)(Wbf + (size_t)(16 * c + lr) * EMB
                                             + 32 * kh + 8 * lk);

    const u16* trow = tbf + (size_t)(row0 + lr) * EMB;
    const short8v afrag0 = *(const short8v*)(trow + 8 * lk);
    const short8v afrag1 = *(const short8v*)(trow + 32 + 8 * lk);

    f32x4 acc[4];
    #pragma unroll
    for (int c = 0; c < 4; ++c) {
        f32x4 z = {0.f, 0.f, 0.f, 0.f};
        z = __builtin_amdgcn_mfma_f32_16x16x32_bf16(afrag0, bfrag[c][0], z, 0, 0, 0);
        z = __builtin_amdgcn_mfma_f32_16x16x32_bf16(afrag1, bfrag[c][1], z, 0, 0, 0);
        acc[c] = z;
    }

    #pragma unroll
    for (int c = 0; c < 4; ++c) {
        #pragma unroll
        for (int r = 0; r < 4; ++r) {
            const int row = row0 + 4 * lk + r;
            const size_t idx = (size_t)row * EMB + 16 * c + lr;
            const float e1v = acc[c][r];
            if (FIRST) {
                const float e2v = (e1v >= 0.f) ? e1v : LEAKY * e1v;
                const float e0v = bf16_lo((u32)ebf[idx]);   // e0 (bf16)
                out[idx] = 0.25f * (e0v + e1v + e2v);
                ebf[idx] = f32_to_bf16_rne(e2v);            // e2 for stage 2
            } else {
                out[idx] += 0.25f * e1v;
            }
        }
    }
}

// ===========================================================================
// Fallback (round-1 proven): atomic SpMM + f32 dense, if ws too small.
// ===========================================================================
__global__ __launch_bounds__(256) void spmm_atomic(
    const float* __restrict__ vals, const int* __restrict__ rows,
    const int* __restrict__ cols, const float* __restrict__ src_a,
    const float* __restrict__ src_b, float* __restrict__ dst)
{
    const int tid  = threadIdx.x;
    const int lane = tid & 63;
    const int e    = blockIdx.x * 4 + (tid >> 6);
    if (e >= N_EDGES) return;
    const float v = vals[e];
    const int   c = cols[e];
    const int   r = rows[e];
    const float* src = (src_b != nullptr && c >= N_USERS)
                           ? src_b + (size_t)(c - N_USERS) * EMB
                           : src_a + (size_t)c * EMB;
    unsafeAtomicAdd(&dst[(size_t)r * EMB + lane], v * src[lane]);
}

template <bool FIRST>
__global__ __launch_bounds__(256) void dense_f32(
    const float* __restrict__ t, const float* __restrict__ W,
    const float* __restrict__ user_emb, const float* __restrict__ item_emb,
    float* __restrict__ e2, float* __restrict__ out)
{
    __shared__ float wT[64][65];
    __shared__ float trow[16][64];

    const int tid = threadIdx.x;
    for (int k = tid; k < 64 * 64; k += 256) {
        const int i = k >> 6, j = k & 63;
        wT[j][i] = W[k];
    }
    const int row_base = blockIdx.x * 16;
    for (int k = tid; k < 16 * 64; k += 256) {
        const int r = k >> 6, j = k & 63;
        const int row = row_base + r;
        trow[r][j] = (row < N_NODES) ? t[(size_t)row * EMB + j] : 0.f;
    }
    __syncthreads();

    const int i  = tid & 63;
    const int r0 = tid >> 6;

    #pragma unroll
    for (int rr = 0; rr < 4; ++rr) {
        const int r   = r0 * 4 + rr;
        const int row = row_base + r;
        if (row >= N_NODES) continue;
        float acc = 0.f;
        #pragma unroll
        for (int j = 0; j < 64; ++j)
            acc = fmaf(trow[r][j], wT[j][i], acc);
        const size_t idx = (size_t)row * EMB + i;
        if (FIRST) {
            const float e1v = acc;
            const float e2v = (e1v >= 0.f) ? e1v : LEAKY * e1v;
            const float e0v = (row < N_USERS)
                                  ? user_emb[idx]
                                  : item_emb[(size_t)(row - N_USERS) * EMB + i];
            e2[idx]  = e2v;
            out[idx] = 0.25f * (e0v + e1v + e2v);
        } else {
            out[idx] += 0.25f * acc;
        }
    }
}

// ===========================================================================
extern "C" void kernel_launch(void* const* d_in, const int* in_sizes, int n_in,
                              void* d_out, int out_size, void* d_ws, size_t ws_size,
                              hipStream_t stream)
{
    const float* user_emb = (const float*)d_in[0];
    const float* item_emb = (const float*)d_in[1];
    const float* W0       = (const float*)d_in[2];
    const float* W1       = (const float*)d_in[3];
    const float* adj_vals = (const float*)d_in[4];
    const int*   adj_rows = (const int*)d_in[5];
    const int*   adj_cols = (const int*)d_in[6];
    float*       out      = (float*)d_out;

    const size_t mat_bytes = (size_t)N_NODES * EMB * sizeof(float);   // 38.4 MB
    const size_t ebf_bytes = (size_t)N_NODES * EMB * sizeof(u16);     // 19.2 MB
    const size_t edge8     = (size_t)N_EDGES * sizeof(float2);        // 19.2 MB
    const size_t hmat      = (size_t)NCH * NBKT * sizeof(int);

    // layout: [tbf 19.2 | svc transient] [sedge 19.2] [ebf 19.2] [aux] [Wbf]
    const size_t off_tbf    = 0;
    const size_t off_svc    = 0;                       // transient, inside tbf
    const size_t off_sedge  = off_tbf + ebf_bytes;
    const size_t off_ebf    = off_sedge + edge8;
    const size_t off_rowptr = off_ebf + ebf_bytes;
    const size_t off_H      = off_rowptr + (size_t)(N_NODES + 1) * sizeof(int);
    const size_t off_B      = off_H + hmat;
    const size_t off_ptr    = off_B + hmat;
    const size_t off_wbf    = (off_ptr + (size_t)(NBKT + 1) * sizeof(int) + 15) & ~(size_t)15;
    const size_t required   = off_wbf + 2 * (size_t)EMB * EMB * sizeof(u16); // ~59.5 MB

    const int spmm_blocks   = (N_NODES + 3) / 4;       // 37500
    const int densem_blocks = (NTILE + 3) / 4;         // 2344
    const int conv_blocks   = (N_NODES * EMB / 4 + 255) / 256;

    if (ws_size >= required) {
        u16*    tbf     = (u16*)((char*)d_ws + off_tbf);
        float2* svc     = (float2*)((char*)d_ws + off_svc);
        float2* sedge   = (float2*)((char*)d_ws + off_sedge);
        u16*    ebf     = (u16*)((char*)d_ws + off_ebf);
        int*    row_ptr = (int*)((char*)d_ws + off_rowptr);
        int*    H       = (int*)((char*)d_ws + off_H);
        int*    B       = (int*)((char*)d_ws + off_B);
        int*    bkt_ptr = (int*)((char*)d_ws + off_ptr);
        u16*    Wbf0    = (u16*)((char*)d_ws + off_wbf);
        u16*    Wbf1    = Wbf0 + EMB * EMB;

        // ---- bf16 sources (e0, W0, W1) ----
        conv_all<<<conv_blocks, 256, 0, stream>>>(
            user_emb, item_emb, W0, W1, ebf, Wbf0, Wbf1);

        // ---- bucket-sorted edge list + row_ptr (once, reused twice) ----
        bkt_hist<<<NCH, 1024, 0, stream>>>(adj_rows, H);
        scan_plus<<<1, 1024, 0, stream>>>(H, bkt_ptr, B);
        partition_l1<<<NCH, 1024, 0, stream>>>(
            adj_vals, adj_rows, adj_cols, B, svc);
        place_l2<<<NBKT, RB, 0, stream>>>(bkt_ptr, svc, sedge, row_ptr);
        // svc (inside tbf) is dead from here on

        // ---- stage 1: tbf = A @ e0 ; e1/e2/out ; e2 -> ebf (bf16) ----
        spmm_bf16<<<spmm_blocks, 256, 0, stream>>>(row_ptr, sedge, ebf, tbf);
        dense_mfma<true><<<densem_blocks, 256, 0, stream>>>(tbf, Wbf0, ebf, out);

        // ---- stage 2: tbf = A @ e2 ; out += 0.25*e3 ----
        spmm_bf16<<<spmm_blocks, 256, 0, stream>>>(row_ptr, sedge, ebf, tbf);
        dense_mfma<false><<<densem_blocks, 256, 0, stream>>>(tbf, Wbf1, ebf, out);
    } else {
        // ---- fallback: round-1 atomic path ----
        float* t  = (float*)d_ws;
        float* e2 = (float*)((char*)d_ws + mat_bytes);
        const int dense_blocks = (N_NODES + 15) / 16;

        hipMemsetAsync(t, 0, mat_bytes, stream);
        spmm_atomic<<<(N_EDGES + 3) / 4, 256, 0, stream>>>(
            adj_vals, adj_rows, adj_cols, user_emb, item_emb, t);
        dense_f32<true><<<dense_blocks, 256, 0, stream>>>(
            t, W0, user_emb, item_emb, e2, out);

        hipMemsetAsync(t, 0, mat_bytes, stream);
        spmm_atomic<<<(N_EDGES + 3) / 4, 256, 0, stream>>>(
            adj_vals, adj_rows, adj_cols, e2, nullptr, t);
        dense_f32<false><<<dense_blocks, 256, 0, stream>>>(
            t, W1, nullptr, nullptr, nullptr, out);
    }
}